// Round 7
// baseline (42.759 us; speedup 1.0000x reference)
//
#include <hip/hip_runtime.h>
#include <math.h>

// Problem geometry (fixed by the reference)
#define NB 2
#define NVOICE 8
#define NN (NB * NVOICE)   // 16 series
#define NH 64              // harmonics
#define NF 500             // frames
#define NT 32000           // samples
#define NCHUNK 32          // angular_cumsum chunks of 1000
#define CHUNK 1000
#define NWIN 500           // one 64-sample window per synthesis block
#define WIN 64

static __device__ __forceinline__ float tpi_f()    { return (float)(6.283185307179586); }
static __device__ __forceinline__ float omc_f()    { return (float)(6.283185307179586 / 16000.0); }
static __device__ __forceinline__ float inv2pi_f() { return (float)(1.0 / 6.283185307179586); }

// DPP add helper
template<int CTRL>
static __device__ __forceinline__ float dpp_add(float x) {
    int y = __builtin_amdgcn_update_dpp(0, __float_as_int(x), CTRL, 0xF, 0xF, true);
    return x + __int_as_float(y);
}
// Sum within each row of 16 lanes; result on ALL lanes of the row.
static __device__ __forceinline__ float row16_sum(float x) {
    x = dpp_add<0xB1>(x);    // quad_perm xor1
    x = dpp_add<0x4E>(x);    // quad_perm xor2
    x = dpp_add<0x141>(x);   // row_half_mirror (sum over 8)
    x = dpp_add<0x140>(x);   // row_mirror      (sum over 16)
    return x;
}

// K1: per-frame harmonic normalization -> ha[f][n][h] (h-coalesced for ksyn).
// Pass 1: lane = frame, coalesced harms loads, LDS transpose. Pass 2: lane = h.
__global__ __launch_bounds__(64) void k1_norm(const float* __restrict__ freqs,
                                              const float* __restrict__ harms,
                                              const float* __restrict__ amps,
                                              float* __restrict__ ha) {
    int blk = blockIdx.x;          // n * 8 + ftile
    int n = blk >> 3, ft = blk & 7;
    int lane = threadIdx.x;
    int f = (ft << 6) + lane;
    int fcl = (f < NF) ? f : NF - 1;
    __shared__ float sh[64][65];   // [local f][h], padded
    __shared__ float denl[64];
    float freq = freqs[n * NF + fcl];
    float den = 0.0f;
    const float* __restrict__ hb = harms + (size_t)n * NH * NF + fcl;
    #pragma unroll 8
    for (int h = 0; h < NH; ++h) {
        float hm = hb[(size_t)h * NF];
        hm = (__fmul_rn(freq, (float)(h + 1)) > 8000.0f) ? 0.0f : hm;
        sh[lane][h] = hm;
        den = __fadd_rn(den, hm);
    }
    denl[lane] = (den == 0.0f) ? 1e-7f : den;
    __syncthreads();
    int h = lane;
    #pragma unroll 8
    for (int ff = 0; ff < 64; ++ff) {
        int fo = (ft << 6) + ff;
        if (fo >= NF) break;
        float hm = sh[ff][h];
        float d  = denl[ff];
        float va = amps[n * NF + fo];                       // uniform -> scalar load
        ha[((size_t)fo * NN + n) * NH + h] = __fmul_rn(va, __fdiv_rn(hm, d));
    }
}

// ---- 64-sample window body for K2: branch-free, per-R constants folded ----
template<bool MASKED, int SP>
static __device__ __forceinline__ void k2_window(float fA, float fB, float fC,
                                                 float& s, int lo, int hi) {
    #pragma unroll
    for (int R = 0; R < 64; ++R) {
        float wy = (float)((R < 32) ? (2 * R + 65) : (2 * R - 63)) * 0.0078125f;
        float wx = 1.0f - wy;
        float h0 = (R < 32) ? fA : fB;
        float h1 = (R < 32) ? fB : fC;
        float fe;
        if (SP == 1 && R < 32)       fe = fB;
        else if (SP == 2 && R >= 32) fe = fB;
        else fe = __fadd_rn(__fmul_rn(h0, wx), __fmul_rn(h1, wy));
        float om = __fmul_rn(fe, omc_f());
        if (MASKED) om = (R >= lo && R < hi) ? om : 0.0f;   // fadd(s,+0)=s exact
        s = __fadd_rn(s, om);
    }
}

// K2: bit-exact f32 omega scan per (n,c); stores exclusive prefix s at every
// 64-aligned window start inside the chunk, and the chunk total mod 2pi.
__global__ __launch_bounds__(64) void k2_chunk_scan(const float* __restrict__ freqs,
                                                    float* __restrict__ substart,
                                                    float* __restrict__ tmod) {
    int n = blockIdx.x >> 5, c = blockIdx.x & 31;
    int h = threadIdx.x;
    const float kf = (float)(h + 1);
    const float* __restrict__ fr = freqs + n * NF;
    const int tbeg = c * CHUNK, tend = tbeg + CHUNK;
    int t = tbeg & ~63;
    int q = t >> 6;
    float vA = fr[(q > 0) ? q - 1 : 0];
    float vB = fr[q];
    float vC = fr[(q + 1 < NF) ? q + 1 : NF - 1];
    float s = 0.0f;
    while (t < tend) {
        q = t >> 6;
        float vNext = fr[(q + 2 < NF) ? q + 2 : NF - 1];    // prefetch next window
        if (t >= tbeg)
            substart[(((size_t)q) * NN + n) * NH + h] = s;  // exclusive prefix at window start
        float fA = __fmul_rn(vA, kf), fB = __fmul_rn(vB, kf), fC = __fmul_rn(vC, kf);
        int lo = tbeg - t;
        int hi = tend - t;
        if (lo <= 0 && hi >= 64) {
            if (q == 0)            k2_window<false, 1>(fA, fB, fC, s, 0, 64);
            else if (q == NF - 1)  k2_window<false, 2>(fA, fB, fC, s, 0, 64);
            else                   k2_window<false, 0>(fA, fB, fC, s, 0, 64);
        } else {
            k2_window<true, 0>(fA, fB, fC, s, (lo > 0) ? lo : 0, (hi < 64) ? hi : 64);
        }
        __builtin_amdgcn_sched_barrier(0);
        vA = vB; vB = vC; vC = vNext;
        t += 64;
    }
    tmod[((size_t)c * NN + n) * NH + h] = fmodf(s, tpi_f());
}

// ---- synthesis slab: 16 samples of one window, fully unrolled ----
template<int SP, bool SPAN, int R0>
static __device__ __forceinline__ void syn_slab16(float fA, float fB, float fC,
                                                  float a0, float a1,
                                                  float& s, float off0r, float off1r, int rb,
                                                  int v, int h,
                                                  const float2* wtab,
                                                  float (*vsum4)[4][WIN + 1]) {
    #pragma unroll
    for (int Ri = 0; Ri < 16; ++Ri) {
        const int R = R0 + Ri;
        float wy = (float)((R < 32) ? (2 * R + 65) : (2 * R - 63)) * 0.0078125f;
        float wx = 1.0f - wy;
        float h0 = (R < 32) ? fA : fB;
        float h1 = (R < 32) ? fB : fC;
        float fe;
        if (SP == 1 && R < 32)       fe = fB;
        else if (SP == 2 && R >= 32) fe = fB;
        else fe = __fadd_rn(__fmul_rn(h0, wx), __fmul_rn(h1, wy));
        float om = __fmul_rn(fe, omc_f());
        if (SPAN) s = (R == rb) ? om : __fadd_rn(s, om);    // cumsum restarts at chunk boundary
        else      s = __fadd_rn(s, om);
        float offr = SPAN ? ((R >= rb) ? off1r : off0r) : off0r;
        float pr = __fmaf_rn(s, inv2pi_f(), offr);
        float fr_, sv;
        asm("v_fract_f32 %0, %1" : "=v"(fr_) : "v"(pr));
        asm("v_sin_f32 %0, %1" : "=v"(sv) : "v"(fr_));      // sin(2pi*frac)
        float2 wab = wtab[R];
        float amp = __fadd_rn(__fmul_rn(a1, wab.x), __fmul_rn(a0, wab.y));
        amp = (fe > 8000.0f) ? 0.0f : amp;
        float ct = row16_sum(__fmul_rn(sv, amp));
        if ((h & 15) == 0) vsum4[v][h >> 4][R] = ct;        // 4 row partials per voice
    }
    __builtin_amdgcn_sched_barrier(0);
}

template<int SP, bool SPAN>
static __device__ __forceinline__ void syn_window(float fA, float fB, float fC,
                                                  float a0, float a1,
                                                  float& s, float off0r, float off1r, int rb,
                                                  int v, int h,
                                                  const float2* wtab,
                                                  float (*vsum4)[4][WIN + 1]) {
    syn_slab16<SP, SPAN, 0 >(fA, fB, fC, a0, a1, s, off0r, off1r, rb, v, h, wtab, vsum4);
    syn_slab16<SP, SPAN, 16>(fA, fB, fC, a0, a1, s, off0r, off1r, rb, v, h, wtab, vsum4);
    syn_slab16<SP, SPAN, 32>(fA, fB, fC, a0, a1, s, off0r, off1r, rb, v, h, wtab, vsum4);
    syn_slab16<SP, SPAN, 48>(fA, fB, fC, a0, a1, s, off0r, off1r, rb, v, h, wtab, vsum4);
}

// KS: synthesis. Block = (b, window q of 64 samples); 512 thr = 8 voices x 64 h.
__global__ __launch_bounds__(512) void ksyn(const float* __restrict__ freqs,
                                            const float* __restrict__ ha,
                                            const float* __restrict__ substart,
                                            const float* __restrict__ tmod,
                                            float* __restrict__ out) {
    int q = blockIdx.x % NWIN;
    int b = blockIdx.x / NWIN;
    int tid = threadIdx.x;
    int v = tid >> 6, h = tid & 63;
    int n = (b << 3) + v;

    __shared__ float2 wtab[64];                      // {win[r], win[64+r]}
    __shared__ float vsum4[NVOICE][4][WIN + 1];      // padded: conflict-free partial stores
    if (tid < 64) {
        float aA = __fmul_rn(tpi_f(), (float)tid) * 0.0078125f;
        float aB = __fmul_rn(tpi_f(), (float)(tid + 64)) * 0.0078125f;
        wtab[tid] = make_float2(0.5f - 0.5f * cosf(aA), 0.5f - 0.5f * cosf(aB));
    }
    __syncthreads();

    const float kf = (float)(h + 1);
    int t0 = q << 6;
    int c0 = t0 / 1000;
    int tb = (c0 + 1) * 1000;                        // next chunk boundary
    bool span = (tb < t0 + WIN);                     // boundary strictly inside window
    int f1 = (q + 1 < NF) ? q + 1 : NF - 1;

    // ---- offsets: fully-unrolled masked accumulation (independent coalesced loads)
    const float* __restrict__ tm = tmod + (size_t)n * NH + h;   // [c][n][h]
    float cum = 0.0f;
    #pragma unroll
    for (int c = 0; c < NCHUNK - 1; ++c) {
        float tv = tm[(size_t)c * NN * NH];
        cum = __fadd_rn(cum, (c < c0) ? tv : 0.0f);  // tmod >= +0, so +0 add is exact identity
    }
    float off0r = __fmul_rn(fmodf(cum, tpi_f()), inv2pi_f());
    float off1r = off0r;
    if (span) {
        float cum2 = __fadd_rn(cum, tm[(size_t)c0 * NN * NH]);
        off1r = __fmul_rn(fmodf(cum2, tpi_f()), inv2pi_f());
    }

    // ---- amp frames (coalesced from ha[f][n][h])
    float a0 = ha[((size_t)q  * NN + n) * NH + h];
    float a1 = ha[((size_t)f1 * NN + n) * NH + h];

    // ---- freq lerp endpoints (frame-level hf, bit-exact)
    const float* __restrict__ fr = freqs + n * NF;
    float fA = __fmul_rn(fr[(q > 0) ? q - 1 : 0], kf);
    float fB = __fmul_rn(fr[q], kf);
    float fC = __fmul_rn(fr[f1], kf);

    float s = substart[((size_t)q * NN + n) * NH + h];

    if (!span) {
        if (q == 0)            syn_window<1, false>(fA, fB, fC, a0, a1, s, off0r, off0r, 64, v, h, wtab, vsum4);
        else if (q == NF - 1)  syn_window<2, false>(fA, fB, fC, a0, a1, s, off0r, off0r, 64, v, h, wtab, vsum4);
        else                   syn_window<0, false>(fA, fB, fC, a0, a1, s, off0r, off0r, 64, v, h, wtab, vsum4);
    } else {
        syn_window<0, true>(fA, fB, fC, a0, a1, s, off0r, off1r, tb - t0, v, h, wtab, vsum4);
    }
    __syncthreads();

    if (tid < WIN) {
        float acc = 0.0f;
        #pragma unroll
        for (int vv = 0; vv < NVOICE; ++vv) {
            #pragma unroll
            for (int rr = 0; rr < 4; ++rr)
                acc = __fadd_rn(acc, vsum4[vv][rr][tid]);
        }
        out[(size_t)b * NT + t0 + tid] = __fmul_rn(0.02f, acc);
    }
}

extern "C" void kernel_launch(void* const* d_in, const int* in_sizes, int n_in,
                              void* d_out, int out_size, void* d_ws, size_t ws_size,
                              hipStream_t stream) {
    (void)in_sizes; (void)n_in; (void)out_size; (void)ws_size;
    const float* freqs = (const float*)d_in[0];   // (2,8,500)
    const float* harms = (const float*)d_in[1];   // (2,8,64,500)
    const float* amps  = (const float*)d_in[2];   // (2,8,500)
    float* out = (float*)d_out;                   // (2,32000)

    // Workspace (floats): ha 512000 + substart 512000 + tmod 32768  (~4.2 MB)
    float* ws = (float*)d_ws;
    float* ha       = ws;                                    // [f][n][h]
    float* substart = ha + (size_t)NF * NN * NH;             // [window q][n][h]
    float* tmod     = substart + (size_t)NWIN * NN * NH;     // [c][n][h]

    hipLaunchKernelGGL(k1_norm, dim3(NN * 8), dim3(64), 0, stream,
                       freqs, harms, amps, ha);
    hipLaunchKernelGGL(k2_chunk_scan, dim3(NN * NCHUNK), dim3(64), 0, stream,
                       freqs, substart, tmod);
    hipLaunchKernelGGL(ksyn, dim3(NB * NWIN), dim3(512), 0, stream,
                       freqs, ha, substart, tmod, out);
}

// Round 8
// 35.037 us; speedup vs baseline: 1.2204x; 1.2204x over previous
//
#include <hip/hip_runtime.h>
#include <math.h>

// Problem geometry (fixed by the reference)
#define NB 2
#define NVOICE 8
#define NN (NB * NVOICE)   // 16 series
#define NH 64              // harmonics
#define NF 500             // frames
#define NT 32000           // samples
#define NCHUNK 32          // angular_cumsum chunks of 1000
#define CHUNK 1000
#define NWIN 500           // one 64-sample window per synthesis block
#define WIN 64
#define K2BLOCKS (NN * NCHUNK)   // 512 chunk-scan blocks
#define K1BLOCKS (NN * 8)        // 128 normalization blocks

static __device__ __forceinline__ float tpi_f()    { return (float)(6.283185307179586); }
static __device__ __forceinline__ float omc_f()    { return (float)(6.283185307179586 / 16000.0); }
static __device__ __forceinline__ float inv2pi_f() { return (float)(1.0 / 6.283185307179586); }

// ---- compile-time Hann window table (f64 Taylor cos, rounded to f32) ----
constexpr double kPIO2 = 1.5707963267948966;
constexpr double d_cos_red(double r) {      // |r| <= pi/4
    double r2 = r * r, term = 1.0, sum = 1.0;
    for (int k = 1; k <= 12; ++k) { term *= -r2 / (double)((2 * k - 1) * (2 * k)); sum += term; }
    return sum;
}
constexpr double d_sin_red(double r) {
    double r2 = r * r, term = r, sum = r;
    for (int k = 1; k <= 12; ++k) { term *= -r2 / (double)((2 * k) * (2 * k + 1)); sum += term; }
    return sum;
}
constexpr double d_cos(double x) {          // x in [0, 2pi)
    int k = 0; double r = x;
    while (r > kPIO2 * 0.5) { r -= kPIO2; ++k; }
    switch (k & 3) {
        case 0: return d_cos_red(r);
        case 1: return -d_sin_red(r);
        case 2: return -d_cos_red(r);
        default: return d_sin_red(r);
    }
}
struct WinT { float wA[64]; float wB[64]; };
constexpr WinT make_win() {
    WinT w{};
    for (int j = 0; j < 64; ++j) {
        // numpy-faithful f32 op order: fl(fl(2pi)*j) * (1/128), all steps f32
        float aA = (float)6.283185307179586 * (float)j * 0.0078125f;
        float aB = (float)6.283185307179586 * (float)(j + 64) * 0.0078125f;
        w.wA[j] = 0.5f - 0.5f * (float)d_cos((double)aA);   // win[r]    -> weights frame q+1
        w.wB[j] = 0.5f - 0.5f * (float)d_cos((double)aB);   // win[64+r] -> weights frame q
    }
    return w;
}
constexpr WinT WT = make_win();

// DPP add helper
template<int CTRL>
static __device__ __forceinline__ float dpp_add(float x) {
    int y = __builtin_amdgcn_update_dpp(0, __float_as_int(x), CTRL, 0xF, 0xF, true);
    return x + __int_as_float(y);
}
// Sum within each row of 16 lanes; result on ALL lanes of the row.
static __device__ __forceinline__ float row16_sum(float x) {
    x = dpp_add<0xB1>(x);    // quad_perm xor1
    x = dpp_add<0x4E>(x);    // quad_perm xor2
    x = dpp_add<0x141>(x);   // row_half_mirror (sum over 8)
    x = dpp_add<0x140>(x);   // row_mirror      (sum over 16)
    return x;
}

// ---- 64-sample window body for K2: branch-free, per-R constants folded ----
template<bool MASKED, int SP>
static __device__ __forceinline__ void k2_window(float fA, float fB, float fC,
                                                 float& s, int lo, int hi) {
    #pragma unroll
    for (int R = 0; R < 64; ++R) {
        float wy = (float)((R < 32) ? (2 * R + 65) : (2 * R - 63)) * 0.0078125f;
        float wx = 1.0f - wy;
        float h0 = (R < 32) ? fA : fB;
        float h1 = (R < 32) ? fB : fC;
        float fe;
        if (SP == 1 && R < 32)       fe = fB;
        else if (SP == 2 && R >= 32) fe = fB;
        else fe = __fadd_rn(__fmul_rn(h0, wx), __fmul_rn(h1, wy));
        float om = __fmul_rn(fe, omc_f());
        if (MASKED) om = (R >= lo && R < hi) ? om : 0.0f;   // fadd(s,+0)=s exact
        s = __fadd_rn(s, om);
    }
}

// K12 fat kernel. Blocks [0, 512): bit-exact f32 omega chunk scan (substart at
// every window start + chunk total mod 2pi). Blocks [512, 640): normalization.
__global__ __launch_bounds__(64) void k12_scan_norm(const float* __restrict__ freqs,
                                                    const float* __restrict__ harms,
                                                    const float* __restrict__ amps,
                                                    float* __restrict__ ha,
                                                    float* __restrict__ substart,
                                                    float* __restrict__ tmod) {
    int blk = blockIdx.x;
    if (blk < K2BLOCKS) {
        // ---- chunk scan ----
        int n = blk >> 5, c = blk & 31;
        int h = threadIdx.x;
        const float kf = (float)(h + 1);
        const float* __restrict__ fr = freqs + n * NF;
        const int tbeg = c * CHUNK, tend = tbeg + CHUNK;
        int t = tbeg & ~63;
        int q = t >> 6;
        float vA = fr[(q > 0) ? q - 1 : 0];
        float vB = fr[q];
        float vC = fr[(q + 1 < NF) ? q + 1 : NF - 1];
        float s = 0.0f;
        while (t < tend) {
            q = t >> 6;
            float vNext = fr[(q + 2 < NF) ? q + 2 : NF - 1];    // prefetch next window
            if (t >= tbeg)
                substart[(((size_t)q) * NN + n) * NH + h] = s;  // exclusive prefix
            float fA = __fmul_rn(vA, kf), fB = __fmul_rn(vB, kf), fC = __fmul_rn(vC, kf);
            int lo = tbeg - t;
            int hi = tend - t;
            if (lo <= 0 && hi >= 64) {
                if (q == 0)            k2_window<false, 1>(fA, fB, fC, s, 0, 64);
                else if (q == NF - 1)  k2_window<false, 2>(fA, fB, fC, s, 0, 64);
                else                   k2_window<false, 0>(fA, fB, fC, s, 0, 64);
            } else {
                k2_window<true, 0>(fA, fB, fC, s, (lo > 0) ? lo : 0, (hi < 64) ? hi : 64);
            }
            vA = vB; vB = vC; vC = vNext;
            t += 64;
        }
        tmod[((size_t)c * NN + n) * NH + h] = fmodf(s, tpi_f());
    } else {
        // ---- normalization -> ha[f][n][h] ----
        int blk2 = blk - K2BLOCKS;     // n * 8 + ftile
        int n = blk2 >> 3, ft = blk2 & 7;
        int lane = threadIdx.x;
        int f = (ft << 6) + lane;
        int fcl = (f < NF) ? f : NF - 1;
        __shared__ float sh[64][65];   // [local f][h], padded
        __shared__ float denl[64];
        float freq = freqs[n * NF + fcl];
        float den = 0.0f;
        const float* __restrict__ hb = harms + (size_t)n * NH * NF + fcl;
        #pragma unroll 8
        for (int h = 0; h < NH; ++h) {
            float hm = hb[(size_t)h * NF];
            hm = (__fmul_rn(freq, (float)(h + 1)) > 8000.0f) ? 0.0f : hm;
            sh[lane][h] = hm;
            den = __fadd_rn(den, hm);
        }
        denl[lane] = (den == 0.0f) ? 1e-7f : den;
        __syncthreads();
        int h = lane;
        #pragma unroll 8
        for (int ff = 0; ff < 64; ++ff) {
            int fo = (ft << 6) + ff;
            if (fo >= NF) break;
            float hm = sh[ff][h];
            float d  = denl[ff];
            float va = amps[n * NF + fo];
            ha[((size_t)fo * NN + n) * NH + h] = __fmul_rn(va, __fdiv_rn(hm, d));
        }
    }
}

// ---- synthesis slab: 16 samples of one window, fully unrolled ----
template<int SP, bool SPAN, int R0>
static __device__ __forceinline__ void syn_slab16(float fA, float fB, float fC,
                                                  float a0, float a1,
                                                  float& s, float off0r, float off1r, int rb,
                                                  int v, int h,
                                                  float (*vsum4)[4][WIN + 1]) {
    #pragma unroll
    for (int Ri = 0; Ri < 16; ++Ri) {
        const int R = R0 + Ri;
        float wy = (float)((R < 32) ? (2 * R + 65) : (2 * R - 63)) * 0.0078125f;
        float wx = 1.0f - wy;
        float h0 = (R < 32) ? fA : fB;
        float h1 = (R < 32) ? fB : fC;
        float fe;
        if (SP == 1 && R < 32)       fe = fB;
        else if (SP == 2 && R >= 32) fe = fB;
        else fe = __fadd_rn(__fmul_rn(h0, wx), __fmul_rn(h1, wy));
        float om = __fmul_rn(fe, omc_f());
        if (SPAN) s = (R == rb) ? om : __fadd_rn(s, om);    // cumsum restarts at chunk boundary
        else      s = __fadd_rn(s, om);
        float offr = SPAN ? ((R >= rb) ? off1r : off0r) : off0r;
        float pr = __fmaf_rn(s, inv2pi_f(), offr);
        float fr_, sv;
        asm("v_fract_f32 %0, %1" : "=v"(fr_) : "v"(pr));
        asm("v_sin_f32 %0, %1" : "=v"(sv) : "v"(fr_));      // sin(2pi*frac)
        float amp = __fadd_rn(__fmul_rn(a1, WT.wA[R]), __fmul_rn(a0, WT.wB[R]));  // literals
        amp = (fe > 8000.0f) ? 0.0f : amp;
        float ct = row16_sum(__fmul_rn(sv, amp));
        if ((h & 15) == 0) vsum4[v][h >> 4][R] = ct;        // 4 row partials per voice
    }
}

template<int SP, bool SPAN>
static __device__ __forceinline__ void syn_window(float fA, float fB, float fC,
                                                  float a0, float a1,
                                                  float& s, float off0r, float off1r, int rb,
                                                  int v, int h,
                                                  float (*vsum4)[4][WIN + 1]) {
    syn_slab16<SP, SPAN, 0 >(fA, fB, fC, a0, a1, s, off0r, off1r, rb, v, h, vsum4);
    syn_slab16<SP, SPAN, 16>(fA, fB, fC, a0, a1, s, off0r, off1r, rb, v, h, vsum4);
    syn_slab16<SP, SPAN, 32>(fA, fB, fC, a0, a1, s, off0r, off1r, rb, v, h, vsum4);
    syn_slab16<SP, SPAN, 48>(fA, fB, fC, a0, a1, s, off0r, off1r, rb, v, h, vsum4);
}

// KS: synthesis. Block = (b, window q of 64 samples); 512 thr = 8 voices x 64 h.
__global__ __launch_bounds__(512) void ksyn(const float* __restrict__ freqs,
                                            const float* __restrict__ ha,
                                            const float* __restrict__ substart,
                                            const float* __restrict__ tmod,
                                            float* __restrict__ out) {
    int q = blockIdx.x % NWIN;
    int b = blockIdx.x / NWIN;
    int tid = threadIdx.x;
    int v = tid >> 6, h = tid & 63;
    int n = (b << 3) + v;

    __shared__ float vsum4[NVOICE][4][WIN + 1];      // padded row partials

    const float kf = (float)(h + 1);
    int t0 = q << 6;
    int c0 = t0 / 1000;
    int tb = (c0 + 1) * 1000;                        // next chunk boundary
    bool span = (tb < t0 + WIN);                     // boundary strictly inside window
    int f1 = (q + 1 < NF) ? q + 1 : NF - 1;

    // ---- offsets: fully-unrolled masked accumulation (independent coalesced loads)
    const float* __restrict__ tm = tmod + (size_t)n * NH + h;   // [c][n][h]
    float cum = 0.0f;
    #pragma unroll
    for (int c = 0; c < NCHUNK - 1; ++c) {
        float tv = tm[(size_t)c * NN * NH];
        cum = __fadd_rn(cum, (c < c0) ? tv : 0.0f);  // +0 add is exact identity (tmod >= +0)
    }
    float off0r = __fmul_rn(fmodf(cum, tpi_f()), inv2pi_f());
    float off1r = off0r;
    if (span) {
        float cum2 = __fadd_rn(cum, tm[(size_t)c0 * NN * NH]);
        off1r = __fmul_rn(fmodf(cum2, tpi_f()), inv2pi_f());
    }

    // ---- amp frames (coalesced from ha[f][n][h])
    float a0 = ha[((size_t)q  * NN + n) * NH + h];
    float a1 = ha[((size_t)f1 * NN + n) * NH + h];

    // ---- freq lerp endpoints (frame-level hf, bit-exact)
    const float* __restrict__ fr = freqs + n * NF;
    float fA = __fmul_rn(fr[(q > 0) ? q - 1 : 0], kf);
    float fB = __fmul_rn(fr[q], kf);
    float fC = __fmul_rn(fr[f1], kf);

    float s = substart[((size_t)q * NN + n) * NH + h];

    if (!span) {
        if (q == 0)            syn_window<1, false>(fA, fB, fC, a0, a1, s, off0r, off0r, 64, v, h, vsum4);
        else if (q == NF - 1)  syn_window<2, false>(fA, fB, fC, a0, a1, s, off0r, off0r, 64, v, h, vsum4);
        else                   syn_window<0, false>(fA, fB, fC, a0, a1, s, off0r, off0r, 64, v, h, vsum4);
    } else {
        syn_window<0, true>(fA, fB, fC, a0, a1, s, off0r, off1r, tb - t0, v, h, vsum4);
    }
    __syncthreads();

    if (tid < WIN) {
        float acc = 0.0f;
        #pragma unroll
        for (int vv = 0; vv < NVOICE; ++vv) {
            #pragma unroll
            for (int rr = 0; rr < 4; ++rr)
                acc = __fadd_rn(acc, vsum4[vv][rr][tid]);
        }
        out[(size_t)b * NT + t0 + tid] = __fmul_rn(0.02f, acc);
    }
}

extern "C" void kernel_launch(void* const* d_in, const int* in_sizes, int n_in,
                              void* d_out, int out_size, void* d_ws, size_t ws_size,
                              hipStream_t stream) {
    (void)in_sizes; (void)n_in; (void)out_size; (void)ws_size;
    const float* freqs = (const float*)d_in[0];   // (2,8,500)
    const float* harms = (const float*)d_in[1];   // (2,8,64,500)
    const float* amps  = (const float*)d_in[2];   // (2,8,500)
    float* out = (float*)d_out;                   // (2,32000)

    // Workspace (floats): ha 512000 + substart 512000 + tmod 32768  (~4.2 MB)
    float* ws = (float*)d_ws;
    float* ha       = ws;                                    // [f][n][h]
    float* substart = ha + (size_t)NF * NN * NH;             // [window q][n][h]
    float* tmod     = substart + (size_t)NWIN * NN * NH;     // [c][n][h]

    hipLaunchKernelGGL(k12_scan_norm, dim3(K2BLOCKS + K1BLOCKS), dim3(64), 0, stream,
                       freqs, harms, amps, ha, substart, tmod);
    hipLaunchKernelGGL(ksyn, dim3(NB * NWIN), dim3(512), 0, stream,
                       freqs, ha, substart, tmod, out);
}

// Round 9
// 33.964 us; speedup vs baseline: 1.2589x; 1.0316x over previous
//
#include <hip/hip_runtime.h>
#include <math.h>

// Problem geometry (fixed by the reference)
#define NB 2
#define NVOICE 8
#define NN (NB * NVOICE)   // 16 series
#define NH 64              // harmonics
#define NF 500             // frames
#define NT 32000           // samples
#define NCHUNK 32          // angular_cumsum chunks of 1000
#define CHUNK 1000
#define NWIN 500           // one 64-sample window per synthesis block
#define WIN 64
#define K2BLOCKS (NN * NCHUNK)   // 512 chunk-scan blocks
#define K1BLOCKS (NN * 8)        // 128 normalization blocks

static __device__ __forceinline__ float tpi_f()    { return (float)(6.283185307179586); }
static __device__ __forceinline__ float omc_f()    { return (float)(6.283185307179586 / 16000.0); }
static __device__ __forceinline__ float inv2pi_f() { return (float)(1.0 / 6.283185307179586); }

// ---- compile-time Hann window table (f64 Taylor cos, rounded to f32) ----
constexpr double kPIO2 = 1.5707963267948966;
constexpr double d_cos_red(double r) {
    double r2 = r * r, term = 1.0, sum = 1.0;
    for (int k = 1; k <= 12; ++k) { term *= -r2 / (double)((2 * k - 1) * (2 * k)); sum += term; }
    return sum;
}
constexpr double d_sin_red(double r) {
    double r2 = r * r, term = r, sum = r;
    for (int k = 1; k <= 12; ++k) { term *= -r2 / (double)((2 * k) * (2 * k + 1)); sum += term; }
    return sum;
}
constexpr double d_cos(double x) {
    int k = 0; double r = x;
    while (r > kPIO2 * 0.5) { r -= kPIO2; ++k; }
    switch (k & 3) {
        case 0: return d_cos_red(r);
        case 1: return -d_sin_red(r);
        case 2: return -d_cos_red(r);
        default: return d_sin_red(r);
    }
}
struct WinT { float wA[64]; float wB[64]; };
constexpr WinT make_win() {
    WinT w{};
    for (int j = 0; j < 64; ++j) {
        float aA = (float)6.283185307179586 * (float)j * 0.0078125f;
        float aB = (float)6.283185307179586 * (float)(j + 64) * 0.0078125f;
        w.wA[j] = 0.5f - 0.5f * (float)d_cos((double)aA);   // win[r]    -> weights frame q+1
        w.wB[j] = 0.5f - 0.5f * (float)d_cos((double)aB);   // win[64+r] -> weights frame q
    }
    return w;
}
constexpr WinT WT = make_win();

// DPP helpers
template<int CTRL, int RMASK>
static __device__ __forceinline__ float dpp0_add(float x) {
    int y = __builtin_amdgcn_update_dpp(0, __float_as_int(x), CTRL, RMASK, 0xF, true);
    return x + __int_as_float(y);
}
// Inclusive 64-lane prefix sum (Hillis-Steele via DPP; non-bit-exact rounding OK here)
static __device__ __forceinline__ float wave_incl_scan(float x) {
    x = dpp0_add<0x111, 0xF>(x);   // row_shr:1
    x = dpp0_add<0x112, 0xF>(x);   // row_shr:2
    x = dpp0_add<0x114, 0xF>(x);   // row_shr:4
    x = dpp0_add<0x118, 0xF>(x);   // row_shr:8
    x = dpp0_add<0x142, 0xa>(x);   // row_bcast:15 -> rows 1,3
    x = dpp0_add<0x143, 0xc>(x);   // row_bcast:31 -> rows 2,3
    return x;
}

// ---- 64-sample window body for K2: branch-free, per-R constants folded ----
template<bool MASKED, int SP>
static __device__ __forceinline__ void k2_window(float fA, float fB, float fC,
                                                 float& s, int lo, int hi) {
    #pragma unroll
    for (int R = 0; R < 64; ++R) {
        float wy = (float)((R < 32) ? (2 * R + 65) : (2 * R - 63)) * 0.0078125f;
        float wx = 1.0f - wy;
        float h0 = (R < 32) ? fA : fB;
        float h1 = (R < 32) ? fB : fC;
        float fe;
        if (SP == 1 && R < 32)       fe = fB;
        else if (SP == 2 && R >= 32) fe = fB;
        else fe = __fadd_rn(__fmul_rn(h0, wx), __fmul_rn(h1, wy));
        float om = __fmul_rn(fe, omc_f());
        if (MASKED) om = (R >= lo && R < hi) ? om : 0.0f;   // fadd(s,+0)=s exact
        s = __fadd_rn(s, om);
    }
}

// K12 fat kernel. Blocks [0, 512): bit-exact f32 omega chunk scan (substart at
// every window start + chunk total mod 2pi). Blocks [512, 640): normalization.
__global__ __launch_bounds__(64) void k12_scan_norm(const float* __restrict__ freqs,
                                                    const float* __restrict__ harms,
                                                    const float* __restrict__ amps,
                                                    float* __restrict__ ha,
                                                    float* __restrict__ substart,
                                                    float* __restrict__ tmod) {
    int blk = blockIdx.x;
    if (blk < K2BLOCKS) {
        int n = blk >> 5, c = blk & 31;
        int h = threadIdx.x;
        const float kf = (float)(h + 1);
        const float* __restrict__ fr = freqs + n * NF;
        const int tbeg = c * CHUNK, tend = tbeg + CHUNK;
        int t = tbeg & ~63;
        int q = t >> 6;
        float vA = fr[(q > 0) ? q - 1 : 0];
        float vB = fr[q];
        float vC = fr[(q + 1 < NF) ? q + 1 : NF - 1];
        float s = 0.0f;
        while (t < tend) {
            q = t >> 6;
            float vNext = fr[(q + 2 < NF) ? q + 2 : NF - 1];
            if (t >= tbeg)
                substart[(((size_t)q) * NN + n) * NH + h] = s;  // exclusive prefix
            float fA = __fmul_rn(vA, kf), fB = __fmul_rn(vB, kf), fC = __fmul_rn(vC, kf);
            int lo = tbeg - t;
            int hi = tend - t;
            if (lo <= 0 && hi >= 64) {
                if (q == 0)            k2_window<false, 1>(fA, fB, fC, s, 0, 64);
                else if (q == NF - 1)  k2_window<false, 2>(fA, fB, fC, s, 0, 64);
                else                   k2_window<false, 0>(fA, fB, fC, s, 0, 64);
            } else {
                k2_window<true, 0>(fA, fB, fC, s, (lo > 0) ? lo : 0, (hi < 64) ? hi : 64);
            }
            vA = vB; vB = vC; vC = vNext;
            t += 64;
        }
        tmod[((size_t)c * NN + n) * NH + h] = fmodf(s, tpi_f());
    } else {
        int blk2 = blk - K2BLOCKS;     // n * 8 + ftile
        int n = blk2 >> 3, ft = blk2 & 7;
        int lane = threadIdx.x;
        int f = (ft << 6) + lane;
        int fcl = (f < NF) ? f : NF - 1;
        __shared__ float sh[64][65];
        __shared__ float denl[64];
        float freq = freqs[n * NF + fcl];
        float den = 0.0f;
        const float* __restrict__ hb = harms + (size_t)n * NH * NF + fcl;
        #pragma unroll 8
        for (int h = 0; h < NH; ++h) {
            float hm = hb[(size_t)h * NF];
            hm = (__fmul_rn(freq, (float)(h + 1)) > 8000.0f) ? 0.0f : hm;
            sh[lane][h] = hm;
            den = __fadd_rn(den, hm);
        }
        denl[lane] = (den == 0.0f) ? 1e-7f : den;
        __syncthreads();
        int h = lane;
        #pragma unroll 8
        for (int ff = 0; ff < 64; ++ff) {
            int fo = (ft << 6) + ff;
            if (fo >= NF) break;
            float hm = sh[ff][h];
            float d  = denl[ff];
            float va = amps[n * NF + fo];
            ha[((size_t)fo * NN + n) * NH + h] = __fmul_rn(va, __fdiv_rn(hm, d));
        }
    }
}

// KS (transposed): lane = sample in window, wave = voice, loop over live harmonics.
__global__ __launch_bounds__(512) void ksyn(const float* __restrict__ freqs,
                                            const float* __restrict__ ha,
                                            const float* __restrict__ substart,
                                            const float* __restrict__ tmod,
                                            float* __restrict__ out) {
    int q = blockIdx.x % NWIN;
    int b = blockIdx.x / NWIN;
    int tid = threadIdx.x;
    int v = tid >> 6, l = tid & 63;
    int n = (b << 3) + v;

    __shared__ float4 pb[NVOICE][NH];      // {base0_rev, base1_rev, a0, a1} per (voice,h)
    __shared__ float vsum[NVOICE][WIN];    // per-voice audio

    int t0 = q << 6;
    int c0 = t0 / 1000;
    int tb = (c0 + 1) * 1000;
    int rb = (tb < t0 + WIN) ? (tb - t0) : 64;   // chunk-boundary lane (64 = none)
    int f1 = (q + 1 < NF) ? q + 1 : NF - 1;

    // ---- prologue, lane role = h ----
    {
        int h = l;
        const float* __restrict__ tm = tmod + (size_t)n * NH + h;   // [c][n][h]
        float cum = 0.0f;
        #pragma unroll
        for (int c = 0; c < NCHUNK - 1; ++c) {
            float tv = tm[(size_t)c * NN * NH];
            cum = __fadd_rn(cum, (c < c0) ? tv : 0.0f);  // +0 exact identity
        }
        float off0 = __fmul_rn(fmodf(cum, tpi_f()), inv2pi_f());
        float off1 = off0;
        if (rb < 64) {
            float cum2 = __fadd_rn(cum, tm[(size_t)c0 * NN * NH]);
            off1 = __fmul_rn(fmodf(cum2, tpi_f()), inv2pi_f());
        }
        float ss = substart[((size_t)q * NN + n) * NH + h];
        float pr0 = __fmaf_rn(ss, inv2pi_f(), off0);
        float b0; asm("v_fract_f32 %0, %1" : "=v"(b0) : "v"(pr0));  // pre-fract: integer revs drop
        float a0 = ha[((size_t)q  * NN + n) * NH + h];
        float a1 = ha[((size_t)f1 * NN + n) * NH + h];
        pb[v][h] = make_float4(b0, off1, a0, a1);
        // wave-private LDS row: no block barrier needed before own-row reads
    }

    // ---- window state, lane role = sample t = t0 + l ----
    const float* __restrict__ fr = freqs + n * NF;
    float vAu = fr[(q > 0) ? q - 1 : 0];     // lane-uniform
    float vBu = fr[q];
    float vCu = fr[f1];
    float wy = (float)((l < 32) ? (2 * l + 65) : (2 * l - 63)) * 0.0078125f;
    float wx = 1.0f - wy;
    bool mlo   = (l < 32);
    bool mEdge = (q == 0 && l < 32) || (q == NF - 1 && l >= 32);
    float wA = WT.wA[l], wB = WT.wB[l];

    // base-freq envelope + one scan per window (phase factoring; tolerance-analyzed)
    float fb0 = mlo ? vAu : vBu;
    float fb1 = mlo ? vBu : vCu;
    float feB = __fadd_rn(__fmul_rn(fb0, wx), __fmul_rn(fb1, wy));
    feB = mEdge ? vBu : feB;
    float scanB = wave_incl_scan(feB);
    float bVal = __int_as_float(__builtin_amdgcn_readlane(__float_as_int(scanB),
                                                          (rb > 0) ? rb - 1 : 0));
    float sbAdj = scanB - ((l >= rb) ? bVal : 0.0f);

    // live-harmonic bound (conservative: +0.5 Hz guard, exact mask still applied per t,h)
    float mnf = fminf(fminf(vAu, vBu), vCu);
    int hmax = min(64, (int)(__fdiv_rn(8000.5f, mnf)));
    hmax = __builtin_amdgcn_readfirstlane(hmax);

    float acc = 0.0f;
    float kf = 1.0f;
    #pragma unroll 4
    for (int hh = 0; hh < hmax; ++hh, kf += 1.0f) {
        float4 pbv = pb[v][hh];                          // uniform broadcast read
        float fA = __fmul_rn(vAu, kf), fB = __fmul_rn(vBu, kf), fC = __fmul_rn(vCu, kf);
        float h0 = mlo ? fA : fB;
        float h1 = mlo ? fB : fC;
        float fe = __fadd_rn(__fmul_rn(h0, wx), __fmul_rn(h1, wy));
        fe = mEdge ? fB : fe;                            // bit-exact freq env (for mask)
        float kor = __fmul_rn(kf, 6.25e-5f);             // (h+1)/16000 rev per unit feBase
        float base = (l >= rb) ? pbv.y : pbv.x;
        float pr = __fmaf_rn(sbAdj, kor, base);
        float fr_, sv;
        asm("v_fract_f32 %0, %1" : "=v"(fr_) : "v"(pr));
        asm("v_sin_f32 %0, %1" : "=v"(sv) : "v"(fr_));   // sin(2pi*frac)
        float amp = __fadd_rn(__fmul_rn(pbv.w, wA), __fmul_rn(pbv.z, wB));
        amp = (fe > 8000.0f) ? 0.0f : amp;               // strict >, bit-exact fe
        acc = __fmaf_rn(sv, amp, acc);
    }
    vsum[v][l] = acc;
    __syncthreads();

    if (tid < WIN) {
        float s8 = 0.0f;
        #pragma unroll
        for (int vv = 0; vv < NVOICE; ++vv) s8 = __fadd_rn(s8, vsum[vv][tid]);
        out[(size_t)b * NT + t0 + tid] = __fmul_rn(0.02f, s8);
    }
}

extern "C" void kernel_launch(void* const* d_in, const int* in_sizes, int n_in,
                              void* d_out, int out_size, void* d_ws, size_t ws_size,
                              hipStream_t stream) {
    (void)in_sizes; (void)n_in; (void)out_size; (void)ws_size;
    const float* freqs = (const float*)d_in[0];   // (2,8,500)
    const float* harms = (const float*)d_in[1];   // (2,8,64,500)
    const float* amps  = (const float*)d_in[2];   // (2,8,500)
    float* out = (float*)d_out;                   // (2,32000)

    // Workspace (floats): ha 512000 + substart 512000 + tmod 32768  (~4.2 MB)
    float* ws = (float*)d_ws;
    float* ha       = ws;                                    // [f][n][h]
    float* substart = ha + (size_t)NF * NN * NH;             // [window q][n][h]
    float* tmod     = substart + (size_t)NWIN * NN * NH;     // [c][n][h]

    hipLaunchKernelGGL(k12_scan_norm, dim3(K2BLOCKS + K1BLOCKS), dim3(64), 0, stream,
                       freqs, harms, amps, ha, substart, tmod);
    hipLaunchKernelGGL(ksyn, dim3(NB * NWIN), dim3(512), 0, stream,
                       freqs, ha, substart, tmod, out);
}